// Round 2
// baseline (438.922 us; speedup 1.0000x reference)
//
#include <hip/hip_runtime.h>

#define IN_DIM  4096
#define OUT_DIM 1024
#define NN      4096
#define MM      8192
#define NSAMP   10

typedef __bf16 bf16x8 __attribute__((ext_vector_type(8)));
typedef float  fx4    __attribute__((ext_vector_type(4)));

__device__ __forceinline__ ushort f2bf(float f) {
    union { float f; unsigned u; } v; v.f = f;
    unsigned u = v.u;
    return (ushort)((u + 0x7FFFu + ((u >> 16) & 1u)) >> 16);
}

// async global->LDS, 16B per lane; LDS dest = wave-uniform base + lane*16
#define GLDS(g, l) __builtin_amdgcn_global_load_lds(                           \
    (const __attribute__((address_space(1))) unsigned*)(g),                    \
    (__attribute__((address_space(3))) unsigned*)(l), 16, 0, 0)

// ---------------------------------------------------------------------------
// K1: v1[k] = sum_o a1[o]*W[o,k];  v2[k] = sum_o a2[o]*W[o,k]
//     + fused: Wbf = bf16(W)  (each element of W is read exactly once here)
// grid (16, 8): x = k-tile of 256, y = o-slice of 128; atomicAdd partials.
// ---------------------------------------------------------------------------
__global__ __launch_bounds__(256) void k_attvec(const float* __restrict__ W,
                                                const float* __restrict__ att,
                                                float* __restrict__ v1,
                                                float* __restrict__ v2,
                                                ushort* __restrict__ Wbf) {
    int k  = blockIdx.x * 256 + threadIdx.x;
    int o0 = blockIdx.y * 128;
    float s1 = 0.f, s2 = 0.f;
    for (int o = o0; o < o0 + 128; ++o) {
        float w = W[(size_t)o * IN_DIM + k];
        Wbf[(size_t)o * IN_DIM + k] = f2bf(w);
        s1 += att[o] * w;
        s2 += att[OUT_DIM + o] * w;
    }
    atomicAdd(&v1[k], s1);
    atomicAdd(&v2[k], s2);
}

// ---------------------------------------------------------------------------
// K2: node_alpha[row] = node_features[row,:] . v1   (one block per row)
// ---------------------------------------------------------------------------
__global__ __launch_bounds__(256) void k_node_alpha(const float* __restrict__ X,
                                                    const float* __restrict__ v1,
                                                    float* __restrict__ outv) {
    int row = blockIdx.x;
    const float4* xr = reinterpret_cast<const float4*>(X + (size_t)row * IN_DIM);
    const float4* vr = reinterpret_cast<const float4*>(v1);
    float s = 0.f;
    for (int i = threadIdx.x; i < IN_DIM / 4; i += 256) {
        float4 a = xr[i], b = vr[i];
        s += a.x * b.x + a.y * b.y + a.z * b.z + a.w * b.w;
    }
    for (int off = 32; off > 0; off >>= 1) s += __shfl_down(s, off, 64);
    __shared__ float ws[4];
    if ((threadIdx.x & 63) == 0) ws[threadIdx.x >> 6] = s;
    __syncthreads();
    if (threadIdx.x == 0) outv[row] = ws[0] + ws[1] + ws[2] + ws[3];
}

// ---------------------------------------------------------------------------
// K3: per neighbor row j: cast fp32 row -> bf16 (GEMM A operand) and
//     neigh_beta[j] = neighbor_features[j,:] . v2  (exact fp32 path)
// ---------------------------------------------------------------------------
__global__ __launch_bounds__(256) void k_cast_beta(const float* __restrict__ X,
                                                   const float* __restrict__ v2,
                                                   ushort* __restrict__ Xbf,
                                                   float* __restrict__ beta) {
    int row = blockIdx.x;
    const float4* xr = reinterpret_cast<const float4*>(X + (size_t)row * IN_DIM);
    const float4* vr = reinterpret_cast<const float4*>(v2);
    ushort4* yr = reinterpret_cast<ushort4*>(Xbf + (size_t)row * IN_DIM);
    float s = 0.f;
    for (int i = threadIdx.x; i < IN_DIM / 4; i += 256) {
        float4 a = xr[i], b = vr[i];
        s += a.x * b.x + a.y * b.y + a.z * b.z + a.w * b.w;
        ushort4 o;
        o.x = f2bf(a.x); o.y = f2bf(a.y); o.z = f2bf(a.z); o.w = f2bf(a.w);
        yr[i] = o;
    }
    for (int off = 32; off > 0; off >>= 1) s += __shfl_down(s, off, 64);
    __shared__ float ws[4];
    if ((threadIdx.x & 63) == 0) ws[threadIdx.x >> 6] = s;
    __syncthreads();
    if (threadIdx.x == 0) beta[row] = ws[0] + ws[1] + ws[2] + ws[3];
}

// ---------------------------------------------------------------------------
// K5: C = A(MM x K, bf16 rm) * B^T, B = Wbf (OUT_DIM x K bf16 rm), C fp32.
// 128x128 tile, BK=32, 4 waves (2x2 of 64x64), 16x16x32 bf16 MFMA.
// Staging via global_load_lds width=16 (m97 ladder step): packed LDS rows of
// 32 elements (64B) — NO padding (GLDS dest is wave-uniform base + lane*16).
// Per iter per wave: 2 A-chunks + 2 B-chunks of 1KB (16 rows each).
// Fragment layouts (HW-verified, learn_hip m89):
//   A/B operand: outer = lane&15, k = (lane>>4)*8 + j
//   C/D:         col   = lane&15, row = (lane>>4)*4 + reg
// ---------------------------------------------------------------------------
#define TM 128
#define TN 128
#define BK 32

__global__ __launch_bounds__(256) void k_gemm(const ushort* __restrict__ A,
                                              const ushort* __restrict__ B,
                                              float* __restrict__ C) {
    __shared__ __align__(16) ushort As[TM * BK];   // 8 KB
    __shared__ __align__(16) ushort Bs[TN * BK];   // 8 KB
    const int tid  = threadIdx.x;
    const int lane = tid & 63;
    const int wave = tid >> 6;
    const int wm   = (wave >> 1) * 64;
    const int wn   = (wave & 1) * 64;
    const int bm   = blockIdx.x * TM;
    const int bn   = blockIdx.y * TN;
    const int quad = lane >> 4;
    const int lrow = lane & 15;

    // staging: wave w stages rows [w*32, w*32+32) of both tiles as 2 chunks
    const int srow  = wave * 32 + (lane >> 2);   // global tile row, chunk 0
    const int skoff = (lane & 3) * 8;            // element offset within row
    const ushort* gA = A + (size_t)(bm + srow) * IN_DIM + skoff;
    const ushort* gB = B + (size_t)(bn + srow) * IN_DIM + skoff;
    ushort* lA = As + wave * 1024;               // chunk 0 LDS base (elements)
    ushort* lB = Bs + wave * 1024;

    fx4 acc[4][4] = {};

    for (int k0 = 0; k0 < IN_DIM; k0 += BK) {
        GLDS(gA + k0,                lA);
        GLDS(gA + k0 + 16 * IN_DIM,  lA + 512);
        GLDS(gB + k0,                lB);
        GLDS(gB + k0 + 16 * IN_DIM,  lB + 512);
        __syncthreads();

        bf16x8 af[4], bfr[4];
#pragma unroll
        for (int mi = 0; mi < 4; ++mi)
            af[mi] = *reinterpret_cast<const bf16x8*>(As + (wm + mi * 16 + lrow) * BK + quad * 8);
#pragma unroll
        for (int ni = 0; ni < 4; ++ni)
            bfr[ni] = *reinterpret_cast<const bf16x8*>(Bs + (wn + ni * 16 + lrow) * BK + quad * 8);
#pragma unroll
        for (int mi = 0; mi < 4; ++mi)
#pragma unroll
            for (int ni = 0; ni < 4; ++ni)
                acc[mi][ni] = __builtin_amdgcn_mfma_f32_16x16x32_bf16(af[mi], bfr[ni], acc[mi][ni], 0, 0, 0);
        __syncthreads();
    }

#pragma unroll
    for (int mi = 0; mi < 4; ++mi)
#pragma unroll
        for (int ni = 0; ni < 4; ++ni) {
            int r = bm + wm + mi * 16 + quad * 4;
            int c = bn + wn + ni * 16 + lrow;
#pragma unroll
            for (int v = 0; v < 4; ++v)
                C[(size_t)(r + v) * OUT_DIM + c] = acc[mi][ni][v];
        }
}

// ---------------------------------------------------------------------------
// K6: per node row: dedupe <=10 neighbor indices (set semantics), softmax of
// leaky_relu(alpha_i + beta_j) over distinct, out = sum w_s * neigh_t[j_s,:]
// ---------------------------------------------------------------------------
__global__ __launch_bounds__(256) void k_aggregate(const float* __restrict__ neigh_t,
                                                   const float* __restrict__ nalpha,
                                                   const float* __restrict__ nbeta,
                                                   const int* __restrict__ nidx,
                                                   float* __restrict__ outp) {
    int row = blockIdx.x;
    __shared__ int   s_idx[NSAMP];
    __shared__ float s_w[NSAMP];
    __shared__ int   s_cnt;
    if (threadIdx.x == 0) {
        int   tmp[NSAMP];
        float sc[NSAMP];
        int   cnt = 0;
        float alpha = nalpha[row];
        float mx = -INFINITY;
        for (int s = 0; s < NSAMP; ++s) {
            int j = nidx[row * NSAMP + s];
            bool dup = false;
            for (int t = 0; t < cnt; ++t)
                if (tmp[t] == j) { dup = true; break; }
            if (!dup) {
                float x = alpha + nbeta[j];
                float v = x > 0.f ? x : 0.2f * x;
                tmp[cnt] = j;
                sc[cnt] = v;
                if (v > mx) mx = v;
                ++cnt;
            }
        }
        float sum = 0.f;
        for (int t = 0; t < cnt; ++t) { float e = expf(sc[t] - mx); sc[t] = e; sum += e; }
        float inv = 1.f / sum;
        for (int t = 0; t < cnt; ++t) { s_idx[t] = tmp[t]; s_w[t] = sc[t] * inv; }
        s_cnt = cnt;
    }
    __syncthreads();
    int cnt = s_cnt;
    int col = threadIdx.x * 4;
    float ax = 0.f, ay = 0.f, az = 0.f, aw = 0.f;
    for (int t = 0; t < cnt; ++t) {
        float w = s_w[t];
        float4 v = *reinterpret_cast<const float4*>(neigh_t + (size_t)s_idx[t] * OUT_DIM + col);
        ax += w * v.x; ay += w * v.y; az += w * v.z; aw += w * v.w;
    }
    float4 o; o.x = ax; o.y = ay; o.z = az; o.w = aw;
    *reinterpret_cast<float4*>(outp + (size_t)row * OUT_DIM + col) = o;
}

// ---------------------------------------------------------------------------
extern "C" void kernel_launch(void* const* d_in, const int* in_sizes, int n_in,
                              void* d_out, int out_size, void* d_ws, size_t ws_size,
                              hipStream_t stream) {
    const float* node_f  = (const float*)d_in[0];  // 4096 x 4096
    const float* neigh_f = (const float*)d_in[1];  // 8192 x 4096
    const float* W       = (const float*)d_in[2];  // 1024 x 4096
    const float* att     = (const float*)d_in[3];  // 2048
    const int*   nidx    = (const int*)d_in[4];    // 4096 x 10
    float* outp = (float*)d_out;                   // 4096 x 1024 fp32

    char* ws = (char*)d_ws;
    ushort* Abf     = (ushort*)ws;                          // 64 MB
    ushort* Wbf     = (ushort*)(ws + 67108864);             // 8 MB
    float*  neigh_t = (float*)(ws + 75497472);              // 32 MB
    float*  v1      = (float*)(ws + 109051904);
    float*  v2      = v1 + IN_DIM;
    float*  nalpha  = v2 + IN_DIM;
    float*  nbeta   = nalpha + NN;

    hipMemsetAsync(v1, 0, 2 * IN_DIM * sizeof(float), stream);

    k_attvec    <<<dim3(16, 8), 256, 0, stream>>>(W, att, v1, v2, Wbf);
    k_node_alpha<<<NN,          256, 0, stream>>>(node_f, v1, nalpha);
    k_cast_beta <<<MM,          256, 0, stream>>>(neigh_f, v2, Abf, nbeta);
    k_gemm      <<<dim3(MM / TM, OUT_DIM / TN), 256, 0, stream>>>(Abf, Wbf, neigh_t);
    k_aggregate <<<NN,          256, 0, stream>>>(neigh_t, nalpha, nbeta, nidx, outp);
}

// Round 3
// 398.890 us; speedup vs baseline: 1.1004x; 1.1004x over previous
//
#include <hip/hip_runtime.h>

#define IN_DIM  4096
#define OUT_DIM 1024
#define NN      4096
#define MM      8192
#define NSAMP   10

typedef __bf16 bf16x8 __attribute__((ext_vector_type(8)));
typedef float  fx4    __attribute__((ext_vector_type(4)));

__device__ __forceinline__ ushort f2bf(float f) {
    union { float f; unsigned u; } v; v.f = f;
    unsigned u = v.u;
    return (ushort)((u + 0x7FFFu + ((u >> 16) & 1u)) >> 16);
}
__device__ __forceinline__ float bf2f(ushort u) {
    union { unsigned u; float f; } v; v.u = ((unsigned)u) << 16;
    return v.f;
}

// async global->LDS, 16B per lane; LDS dest = wave-uniform base + lane*16
#define GLDS(g, l) __builtin_amdgcn_global_load_lds(                           \
    (const __attribute__((address_space(1))) unsigned*)(g),                    \
    (__attribute__((address_space(3))) unsigned*)(l), 16, 0, 0)

// ---------------------------------------------------------------------------
// K1: v1[k] = sum_o a1[o]*W[o,k];  v2[k] = sum_o a2[o]*W[o,k]
//     + fused: Wbf = bf16(W)  (W read exactly once here)
// ---------------------------------------------------------------------------
__global__ __launch_bounds__(256) void k_attvec(const float* __restrict__ W,
                                                const float* __restrict__ att,
                                                float* __restrict__ v1,
                                                float* __restrict__ v2,
                                                ushort* __restrict__ Wbf) {
    int k  = blockIdx.x * 256 + threadIdx.x;
    int o0 = blockIdx.y * 128;
    float s1 = 0.f, s2 = 0.f;
    for (int o = o0; o < o0 + 128; ++o) {
        float w = W[(size_t)o * IN_DIM + k];
        Wbf[(size_t)o * IN_DIM + k] = f2bf(w);
        s1 += att[o] * w;
        s2 += att[OUT_DIM + o] * w;
    }
    atomicAdd(&v1[k], s1);
    atomicAdd(&v2[k], s2);
}

// ---------------------------------------------------------------------------
// K2: node_alpha[row] = node_features[row,:] . v1   (one block per row)
// ---------------------------------------------------------------------------
__global__ __launch_bounds__(256) void k_node_alpha(const float* __restrict__ X,
                                                    const float* __restrict__ v1,
                                                    float* __restrict__ outv) {
    int row = blockIdx.x;
    const float4* xr = reinterpret_cast<const float4*>(X + (size_t)row * IN_DIM);
    const float4* vr = reinterpret_cast<const float4*>(v1);
    float s = 0.f;
    for (int i = threadIdx.x; i < IN_DIM / 4; i += 256) {
        float4 a = xr[i], b = vr[i];
        s += a.x * b.x + a.y * b.y + a.z * b.z + a.w * b.w;
    }
    for (int off = 32; off > 0; off >>= 1) s += __shfl_down(s, off, 64);
    __shared__ float ws[4];
    if ((threadIdx.x & 63) == 0) ws[threadIdx.x >> 6] = s;
    __syncthreads();
    if (threadIdx.x == 0) outv[row] = ws[0] + ws[1] + ws[2] + ws[3];
}

// ---------------------------------------------------------------------------
// K3: per neighbor row j: cast fp32 row -> bf16 (GEMM A operand) and
//     neigh_beta[j] = neighbor_features[j,:] . v2  (exact fp32 path)
// ---------------------------------------------------------------------------
__global__ __launch_bounds__(256) void k_cast_beta(const float* __restrict__ X,
                                                   const float* __restrict__ v2,
                                                   ushort* __restrict__ Xbf,
                                                   float* __restrict__ beta) {
    int row = blockIdx.x;
    const float4* xr = reinterpret_cast<const float4*>(X + (size_t)row * IN_DIM);
    const float4* vr = reinterpret_cast<const float4*>(v2);
    ushort4* yr = reinterpret_cast<ushort4*>(Xbf + (size_t)row * IN_DIM);
    float s = 0.f;
    for (int i = threadIdx.x; i < IN_DIM / 4; i += 256) {
        float4 a = xr[i], b = vr[i];
        s += a.x * b.x + a.y * b.y + a.z * b.z + a.w * b.w;
        ushort4 o;
        o.x = f2bf(a.x); o.y = f2bf(a.y); o.z = f2bf(a.z); o.w = f2bf(a.w);
        yr[i] = o;
    }
    for (int off = 32; off > 0; off >>= 1) s += __shfl_down(s, off, 64);
    __shared__ float ws[4];
    if ((threadIdx.x & 63) == 0) ws[threadIdx.x >> 6] = s;
    __syncthreads();
    if (threadIdx.x == 0) beta[row] = ws[0] + ws[1] + ws[2] + ws[3];
}

// ---------------------------------------------------------------------------
// K5: split-K x2 GEMM.  Pz = A(MM x K/2 slice, bf16 rm) * B^T slice, bf16 out.
// B = Wbf (OUT_DIM x K bf16 rm).  blockIdx.z selects K-half; partial sums
// stored bf16 to P + z*MM*OUT_DIM, summed in k_aggregate.
// Grid (64,8,2) = 1024 blocks = 4 blocks/CU — m97's verified occupancy point.
// m97 2-barrier GLDS structure: 128x128 tile, BK=32, 4 waves (2x2 of 64x64),
// 16x16x32 bf16 MFMA, packed 64B LDS rows (GLDS dest = wave base + lane*16).
// Fragment layouts (HW-verified, learn_hip m89):
//   A/B operand: outer = lane&15, k = (lane>>4)*8 + j
//   C/D:         col   = lane&15, row = (lane>>4)*4 + reg
// ---------------------------------------------------------------------------
#define TM 128
#define TN 128
#define BK 32
#define KSPLIT (IN_DIM / 2)

__global__ __launch_bounds__(256, 4) void k_gemm(const ushort* __restrict__ A,
                                                 const ushort* __restrict__ B,
                                                 ushort* __restrict__ P) {
    __shared__ __align__(16) ushort As[TM * BK];   // 8 KB
    __shared__ __align__(16) ushort Bs[TN * BK];   // 8 KB
    const int tid  = threadIdx.x;
    const int lane = tid & 63;
    const int wave = tid >> 6;
    const int wm   = (wave >> 1) * 64;
    const int wn   = (wave & 1) * 64;
    const int bm   = blockIdx.x * TM;
    const int bn   = blockIdx.y * TN;
    const int kb   = blockIdx.z * KSPLIT;
    const int quad = lane >> 4;
    const int lrow = lane & 15;

    // staging: wave w stages rows [w*32, w*32+32) of both tiles as 2 chunks
    const int srow  = wave * 32 + (lane >> 2);   // global tile row, chunk 0
    const int skoff = (lane & 3) * 8;            // element offset within row
    const ushort* gA = A + (size_t)(bm + srow) * IN_DIM + kb + skoff;
    const ushort* gB = B + (size_t)(bn + srow) * IN_DIM + kb + skoff;
    ushort* lA = As + wave * 1024;               // chunk 0 LDS base (elements)
    ushort* lB = Bs + wave * 1024;

    fx4 acc[4][4] = {};

    for (int k0 = 0; k0 < KSPLIT; k0 += BK) {
        GLDS(gA + k0,                lA);
        GLDS(gA + k0 + 16 * IN_DIM,  lA + 512);
        GLDS(gB + k0,                lB);
        GLDS(gB + k0 + 16 * IN_DIM,  lB + 512);
        __syncthreads();

        bf16x8 af[4], bfr[4];
#pragma unroll
        for (int mi = 0; mi < 4; ++mi)
            af[mi] = *reinterpret_cast<const bf16x8*>(As + (wm + mi * 16 + lrow) * BK + quad * 8);
#pragma unroll
        for (int ni = 0; ni < 4; ++ni)
            bfr[ni] = *reinterpret_cast<const bf16x8*>(Bs + (wn + ni * 16 + lrow) * BK + quad * 8);
#pragma unroll
        for (int mi = 0; mi < 4; ++mi)
#pragma unroll
            for (int ni = 0; ni < 4; ++ni)
                acc[mi][ni] = __builtin_amdgcn_mfma_f32_16x16x32_bf16(af[mi], bfr[ni], acc[mi][ni], 0, 0, 0);
        __syncthreads();
    }

    ushort* Pz = P + (size_t)blockIdx.z * MM * OUT_DIM;
#pragma unroll
    for (int mi = 0; mi < 4; ++mi)
#pragma unroll
        for (int ni = 0; ni < 4; ++ni) {
            int r = bm + wm + mi * 16 + quad * 4;
            int c = bn + wn + ni * 16 + lrow;
#pragma unroll
            for (int v = 0; v < 4; ++v)
                Pz[(size_t)(r + v) * OUT_DIM + c] = f2bf(acc[mi][ni][v]);
        }
}

// ---------------------------------------------------------------------------
// K6: per node row: dedupe <=10 neighbor indices (set semantics), softmax of
// leaky_relu(alpha_i + beta_j) over distinct,
// out = sum_s w_s * (P0[j_s,:] + P1[j_s,:])   (split-K partial add fused)
// ---------------------------------------------------------------------------
__global__ __launch_bounds__(256) void k_aggregate(const ushort* __restrict__ P,
                                                   const float* __restrict__ nalpha,
                                                   const float* __restrict__ nbeta,
                                                   const int* __restrict__ nidx,
                                                   float* __restrict__ outp) {
    int row = blockIdx.x;
    __shared__ int   s_idx[NSAMP];
    __shared__ float s_w[NSAMP];
    __shared__ int   s_cnt;
    if (threadIdx.x == 0) {
        int   tmp[NSAMP];
        float sc[NSAMP];
        int   cnt = 0;
        float alpha = nalpha[row];
        float mx = -INFINITY;
        for (int s = 0; s < NSAMP; ++s) {
            int j = nidx[row * NSAMP + s];
            bool dup = false;
            for (int t = 0; t < cnt; ++t)
                if (tmp[t] == j) { dup = true; break; }
            if (!dup) {
                float x = alpha + nbeta[j];
                float v = x > 0.f ? x : 0.2f * x;
                tmp[cnt] = j;
                sc[cnt] = v;
                if (v > mx) mx = v;
                ++cnt;
            }
        }
        float sum = 0.f;
        for (int t = 0; t < cnt; ++t) { float e = expf(sc[t] - mx); sc[t] = e; sum += e; }
        float inv = 1.f / sum;
        for (int t = 0; t < cnt; ++t) { s_idx[t] = tmp[t]; s_w[t] = sc[t] * inv; }
        s_cnt = cnt;
    }
    __syncthreads();
    int cnt = s_cnt;
    int col = threadIdx.x * 4;
    float ax = 0.f, ay = 0.f, az = 0.f, aw = 0.f;
    for (int t = 0; t < cnt; ++t) {
        float w = s_w[t];
        size_t off = (size_t)s_idx[t] * OUT_DIM + col;
        ushort4 u0 = *reinterpret_cast<const ushort4*>(P + off);
        ushort4 u1 = *reinterpret_cast<const ushort4*>(P + (size_t)MM * OUT_DIM + off);
        ax += w * (bf2f(u0.x) + bf2f(u1.x));
        ay += w * (bf2f(u0.y) + bf2f(u1.y));
        az += w * (bf2f(u0.z) + bf2f(u1.z));
        aw += w * (bf2f(u0.w) + bf2f(u1.w));
    }
    float4 o; o.x = ax; o.y = ay; o.z = az; o.w = aw;
    *reinterpret_cast<float4*>(outp + (size_t)row * OUT_DIM + col) = o;
}

// ---------------------------------------------------------------------------
extern "C" void kernel_launch(void* const* d_in, const int* in_sizes, int n_in,
                              void* d_out, int out_size, void* d_ws, size_t ws_size,
                              hipStream_t stream) {
    const float* node_f  = (const float*)d_in[0];  // 4096 x 4096
    const float* neigh_f = (const float*)d_in[1];  // 8192 x 4096
    const float* W       = (const float*)d_in[2];  // 1024 x 4096
    const float* att     = (const float*)d_in[3];  // 2048
    const int*   nidx    = (const int*)d_in[4];    // 4096 x 10
    float* outp = (float*)d_out;                   // 4096 x 1024 fp32

    char* ws = (char*)d_ws;
    ushort* Abf = (ushort*)ws;                     // 64 MB bf16 A
    ushort* Wbf = (ushort*)(ws + 67108864);        // 8 MB  bf16 W
    ushort* P   = (ushort*)(ws + 75497472);        // 2 x 16 MB bf16 partials
    float*  v1     = (float*)(ws + 109051904);
    float*  v2     = v1 + IN_DIM;
    float*  nalpha = v2 + IN_DIM;
    float*  nbeta  = nalpha + NN;

    hipMemsetAsync(v1, 0, 2 * IN_DIM * sizeof(float), stream);

    k_attvec    <<<dim3(16, 8), 256, 0, stream>>>(W, att, v1, v2, Wbf);
    k_node_alpha<<<NN,          256, 0, stream>>>(node_f, v1, nalpha);
    k_cast_beta <<<MM,          256, 0, stream>>>(neigh_f, v2, Abf, nbeta);
    k_gemm      <<<dim3(MM / TM, OUT_DIM / TN, 2), 256, 0, stream>>>(Abf, Wbf, P);
    k_aggregate <<<NN,          256, 0, stream>>>(P, nalpha, nbeta, nidx, outp);
}

// Round 4
// 381.124 us; speedup vs baseline: 1.1517x; 1.0466x over previous
//
#include <hip/hip_runtime.h>

#define IN_DIM  4096
#define OUT_DIM 1024
#define NN      4096
#define MM      8192
#define NSAMP   10

typedef __bf16 bf16x8 __attribute__((ext_vector_type(8)));
typedef float  fx4    __attribute__((ext_vector_type(4)));

__device__ __forceinline__ ushort f2bf(float f) {
    union { float f; unsigned u; } v; v.f = f;
    unsigned u = v.u;
    return (ushort)((u + 0x7FFFu + ((u >> 16) & 1u)) >> 16);
}
__device__ __forceinline__ float bf2f(ushort u) {
    union { unsigned u; float f; } v; v.u = ((unsigned)u) << 16;
    return v.f;
}

// async global->LDS, 16B per lane; LDS dest = wave-uniform base + lane*16
#define GLDS(g, l) __builtin_amdgcn_global_load_lds(                           \
    (const __attribute__((address_space(1))) unsigned*)(g),                    \
    (__attribute__((address_space(3))) unsigned*)(l), 16, 0, 0)

// ---------------------------------------------------------------------------
// K1: v1[k] = sum_o a1[o]*W[o,k];  v2[k] = sum_o a2[o]*W[o,k]
//     + fused: Wbf = bf16(W)  (W read exactly once here)
// grid (16,16): x = k-tile of 256, y = o-slice of 64; atomicAdd partials.
// ---------------------------------------------------------------------------
__global__ __launch_bounds__(256) void k_attvec(const float* __restrict__ W,
                                                const float* __restrict__ att,
                                                float* __restrict__ v1,
                                                float* __restrict__ v2,
                                                ushort* __restrict__ Wbf) {
    int k  = blockIdx.x * 256 + threadIdx.x;
    int o0 = blockIdx.y * 64;
    float s1 = 0.f, s2 = 0.f;
    for (int o = o0; o < o0 + 64; ++o) {
        float w = W[(size_t)o * IN_DIM + k];
        Wbf[(size_t)o * IN_DIM + k] = f2bf(w);
        s1 += att[o] * w;
        s2 += att[OUT_DIM + o] * w;
    }
    atomicAdd(&v1[k], s1);
    atomicAdd(&v2[k], s2);
}

// ---------------------------------------------------------------------------
// K2 (fused): one block per row over NN + MM rows.
//   row < NN:  nalpha[row] = node_f[row,:] . v1
//   row >= NN: j = row-NN;  nbeta[j] = neigh_f[j,:] . v2  AND Abf[j,:] = bf16
// ---------------------------------------------------------------------------
__global__ __launch_bounds__(256) void k_rows(const float* __restrict__ node_f,
                                              const float* __restrict__ neigh_f,
                                              const float* __restrict__ v1,
                                              const float* __restrict__ v2,
                                              float* __restrict__ nalpha,
                                              float* __restrict__ nbeta,
                                              ushort* __restrict__ Abf) {
    int row = blockIdx.x;
    float s = 0.f;
    if (row < NN) {
        const float4* xr = reinterpret_cast<const float4*>(node_f + (size_t)row * IN_DIM);
        const float4* vr = reinterpret_cast<const float4*>(v1);
        for (int i = threadIdx.x; i < IN_DIM / 4; i += 256) {
            float4 a = xr[i], b = vr[i];
            s += a.x * b.x + a.y * b.y + a.z * b.z + a.w * b.w;
        }
    } else {
        int j = row - NN;
        const float4* xr = reinterpret_cast<const float4*>(neigh_f + (size_t)j * IN_DIM);
        const float4* vr = reinterpret_cast<const float4*>(v2);
        ushort4* yr = reinterpret_cast<ushort4*>(Abf + (size_t)j * IN_DIM);
        for (int i = threadIdx.x; i < IN_DIM / 4; i += 256) {
            float4 a = xr[i], b = vr[i];
            s += a.x * b.x + a.y * b.y + a.z * b.z + a.w * b.w;
            ushort4 o;
            o.x = f2bf(a.x); o.y = f2bf(a.y); o.z = f2bf(a.z); o.w = f2bf(a.w);
            yr[i] = o;
        }
    }
    for (int off = 32; off > 0; off >>= 1) s += __shfl_down(s, off, 64);
    __shared__ float ws[4];
    if ((threadIdx.x & 63) == 0) ws[threadIdx.x >> 6] = s;
    __syncthreads();
    if (threadIdx.x == 0) {
        float t = ws[0] + ws[1] + ws[2] + ws[3];
        if (row < NN) nalpha[row] = t; else nbeta[row - NN] = t;
    }
}

// ---------------------------------------------------------------------------
// K5: split-K x2 GEMM (unchanged from R3 — 95us, 723 TF, proven).
// Pz = A(MM x K/2 slice, bf16 rm) * B^T slice, bf16 out to P + z*MM*OUT_DIM.
// Grid (64,8,2) = 1024 blocks; occupancy is register-capped at ~4 blocks/CU
// (acc 64 AGPR + 56 VGPR = 120 regs -> 4 waves/SIMD).
// m97 2-barrier GLDS structure: 128x128 tile, BK=32, 4 waves (2x2 of 64x64),
// 16x16x32 bf16 MFMA, packed 64B LDS rows (GLDS dest = wave base + lane*16).
// Fragment layouts (HW-verified, learn_hip m89):
//   A/B operand: outer = lane&15, k = (lane>>4)*8 + j
//   C/D:         col   = lane&15, row = (lane>>4)*4 + reg
// ---------------------------------------------------------------------------
#define TM 128
#define TN 128
#define BK 32
#define KSPLIT (IN_DIM / 2)

__global__ __launch_bounds__(256, 4) void k_gemm(const ushort* __restrict__ A,
                                                 const ushort* __restrict__ B,
                                                 ushort* __restrict__ P) {
    __shared__ __align__(16) ushort As[TM * BK];   // 8 KB
    __shared__ __align__(16) ushort Bs[TN * BK];   // 8 KB
    const int tid  = threadIdx.x;
    const int lane = tid & 63;
    const int wave = tid >> 6;
    const int wm   = (wave >> 1) * 64;
    const int wn   = (wave & 1) * 64;
    const int bm   = blockIdx.x * TM;
    const int bn   = blockIdx.y * TN;
    const int kb   = blockIdx.z * KSPLIT;
    const int quad = lane >> 4;
    const int lrow = lane & 15;

    const int srow  = wave * 32 + (lane >> 2);
    const int skoff = (lane & 3) * 8;
    const ushort* gA = A + (size_t)(bm + srow) * IN_DIM + kb + skoff;
    const ushort* gB = B + (size_t)(bn + srow) * IN_DIM + kb + skoff;
    ushort* lA = As + wave * 1024;
    ushort* lB = Bs + wave * 1024;

    fx4 acc[4][4] = {};

    for (int k0 = 0; k0 < KSPLIT; k0 += BK) {
        GLDS(gA + k0,                lA);
        GLDS(gA + k0 + 16 * IN_DIM,  lA + 512);
        GLDS(gB + k0,                lB);
        GLDS(gB + k0 + 16 * IN_DIM,  lB + 512);
        __syncthreads();

        bf16x8 af[4], bfr[4];
#pragma unroll
        for (int mi = 0; mi < 4; ++mi)
            af[mi] = *reinterpret_cast<const bf16x8*>(As + (wm + mi * 16 + lrow) * BK + quad * 8);
#pragma unroll
        for (int ni = 0; ni < 4; ++ni)
            bfr[ni] = *reinterpret_cast<const bf16x8*>(Bs + (wn + ni * 16 + lrow) * BK + quad * 8);
#pragma unroll
        for (int mi = 0; mi < 4; ++mi)
#pragma unroll
            for (int ni = 0; ni < 4; ++ni)
                acc[mi][ni] = __builtin_amdgcn_mfma_f32_16x16x32_bf16(af[mi], bfr[ni], acc[mi][ni], 0, 0, 0);
        __syncthreads();
    }

    ushort* Pz = P + (size_t)blockIdx.z * MM * OUT_DIM;
#pragma unroll
    for (int mi = 0; mi < 4; ++mi)
#pragma unroll
        for (int ni = 0; ni < 4; ++ni) {
            int r = bm + wm + mi * 16 + quad * 4;
            int c = bn + wn + ni * 16 + lrow;
#pragma unroll
            for (int v = 0; v < 4; ++v)
                Pz[(size_t)(r + v) * OUT_DIM + c] = f2bf(acc[mi][ni][v]);
        }
}

// ---------------------------------------------------------------------------
// K6: parallel prologue — lanes 0..9 of wave 0 load idx/beta, dedupe via
// shfl (dup -> weight 0 == reference set semantics), softmax via shfl over
// 16 lanes.  Then all 256 threads gather: out = sum_t w_t*(P0[j_t]+P1[j_t]).
// ---------------------------------------------------------------------------
__global__ __launch_bounds__(256) void k_aggregate(const ushort* __restrict__ P,
                                                   const float* __restrict__ nalpha,
                                                   const float* __restrict__ nbeta,
                                                   const int* __restrict__ nidx,
                                                   float* __restrict__ outp) {
    int row = blockIdx.x;
    __shared__ int   s_idx[NSAMP];
    __shared__ float s_w[NSAMP];
    if (threadIdx.x < 16) {
        int t = threadIdx.x;
        int j = (t < NSAMP) ? nidx[row * NSAMP + t] : -1;
        float score = -INFINITY;
        if (t < NSAMP) {
            float x = nalpha[row] + nbeta[j];
            score = x > 0.f ? x : 0.2f * x;
        }
        // dup if any earlier lane has same index
        bool dup = false;
#pragma unroll
        for (int sIdx = 0; sIdx < NSAMP; ++sIdx) {
            int js = __shfl(j, sIdx, 16);
            if (sIdx < t && js == j) dup = true;
        }
        // max over lanes (dups still carry their score; harmless for max
        // since an identical non-dup copy exists)
        float mx = score;
#pragma unroll
        for (int off = 8; off > 0; off >>= 1) {
            float o = __shfl_xor(mx, off, 16);
            mx = o > mx ? o : mx;
        }
        float e = (t < NSAMP && !dup) ? expf(score - mx) : 0.f;
        float sum = e;
#pragma unroll
        for (int off = 8; off > 0; off >>= 1) sum += __shfl_xor(sum, off, 16);
        if (t < NSAMP) {
            s_idx[t] = j;
            s_w[t]   = e / sum;
        }
    }
    __syncthreads();
    int col = threadIdx.x * 4;
    float ax = 0.f, ay = 0.f, az = 0.f, aw = 0.f;
#pragma unroll
    for (int t = 0; t < NSAMP; ++t) {
        float w = s_w[t];
        size_t off = (size_t)s_idx[t] * OUT_DIM + col;
        ushort4 u0 = *reinterpret_cast<const ushort4*>(P + off);
        ushort4 u1 = *reinterpret_cast<const ushort4*>(P + (size_t)MM * OUT_DIM + off);
        ax += w * (bf2f(u0.x) + bf2f(u1.x));
        ay += w * (bf2f(u0.y) + bf2f(u1.y));
        az += w * (bf2f(u0.z) + bf2f(u1.z));
        aw += w * (bf2f(u0.w) + bf2f(u1.w));
    }
    float4 o; o.x = ax; o.y = ay; o.z = az; o.w = aw;
    *reinterpret_cast<float4*>(outp + (size_t)row * OUT_DIM + col) = o;
}

// ---------------------------------------------------------------------------
extern "C" void kernel_launch(void* const* d_in, const int* in_sizes, int n_in,
                              void* d_out, int out_size, void* d_ws, size_t ws_size,
                              hipStream_t stream) {
    const float* node_f  = (const float*)d_in[0];  // 4096 x 4096
    const float* neigh_f = (const float*)d_in[1];  // 8192 x 4096
    const float* W       = (const float*)d_in[2];  // 1024 x 4096
    const float* att     = (const float*)d_in[3];  // 2048
    const int*   nidx    = (const int*)d_in[4];    // 4096 x 10
    float* outp = (float*)d_out;                   // 4096 x 1024 fp32

    char* ws = (char*)d_ws;
    ushort* Abf = (ushort*)ws;                     // 64 MB bf16 A
    ushort* Wbf = (ushort*)(ws + 67108864);        // 8 MB  bf16 W
    ushort* P   = (ushort*)(ws + 75497472);        // 2 x 16 MB bf16 partials
    float*  v1     = (float*)(ws + 109051904);
    float*  v2     = v1 + IN_DIM;
    float*  nalpha = v2 + IN_DIM;
    float*  nbeta  = nalpha + NN;

    hipMemsetAsync(v1, 0, 2 * IN_DIM * sizeof(float), stream);

    k_attvec   <<<dim3(16, 16), 256, 0, stream>>>(W, att, v1, v2, Wbf);
    k_rows     <<<NN + MM,      256, 0, stream>>>(node_f, neigh_f, v1, v2, nalpha, nbeta, Abf);
    k_gemm     <<<dim3(MM / TM, OUT_DIM / TN, 2), 256, 0, stream>>>(Abf, Wbf, P);
    k_aggregate<<<NN,           256, 0, stream>>>(P, nalpha, nbeta, nidx, outp);
}